// Round 1
// baseline (711.965 us; speedup 1.0000x reference)
//
#include <hip/hip_runtime.h>

typedef unsigned int u32;
typedef unsigned short u16;
typedef __bf16 bf16x8 __attribute__((ext_vector_type(8)));
typedef float f32x4 __attribute__((ext_vector_type(4)));

// ---------- helpers ----------

__device__ __forceinline__ u16 f2bf(float f) {
  u32 u = __builtin_bit_cast(u32, f);
  u32 r = u + 0x7fffu + ((u >> 16) & 1u);  // RNE
  return (u16)(r >> 16);
}

__device__ __forceinline__ void gload_lds16(const void* g, void* l) {
  __builtin_amdgcn_global_load_lds(
      (__attribute__((address_space(1))) void*)(g),
      (__attribute__((address_space(3))) void*)(l), 16, 0, 0);
}

// ---------- fp32 -> bf16 conversion (hs + 4 weights) ----------
// hs: 16777216 elems (2097152 threads), each W: 4194304 elems (524288 threads)

__global__ __launch_bounds__(256) void convert_kernel(
    const float* __restrict__ hs, const float* __restrict__ wq,
    const float* __restrict__ wk, const float* __restrict__ wv,
    const float* __restrict__ wo,
    u16* __restrict__ hsb, u16* __restrict__ wqb, u16* __restrict__ wkb,
    u16* __restrict__ wvb, u16* __restrict__ wob) {
  long t = (long)blockIdx.x * 256 + threadIdx.x;
  const float* src;
  u16* dst;
  long off;
  if (t < 2097152) {
    src = hs; dst = hsb; off = t << 3;
  } else {
    long u = t - 2097152;
    int wi = (int)(u >> 19);
    off = (u & 524287) << 3;
    if (wi == 0)      { src = wq; dst = wqb; }
    else if (wi == 1) { src = wk; dst = wkb; }
    else if (wi == 2) { src = wv; dst = wvb; }
    else              { src = wo; dst = wob; }
  }
  float4 a = *(const float4*)(src + off);
  float4 b = *(const float4*)(src + off + 4);
  uint4 o;
  o.x = (u32)f2bf(a.x) | ((u32)f2bf(a.y) << 16);
  o.y = (u32)f2bf(a.z) | ((u32)f2bf(a.w) << 16);
  o.z = (u32)f2bf(b.x) | ((u32)f2bf(b.y) << 16);
  o.w = (u32)f2bf(b.z) | ((u32)f2bf(b.w) << 16);
  *(uint4*)(dst + off) = o;
}

// ---------- GEMM C[8192x2048] = A[8192x2048] * B[2048x2048]^T + bias ----------
// m97 structure: 128x128 tile, BK=32, 4 waves (2x2), global_load_lds(16B),
// 16 MFMA 16x16x32 per K-step per wave.

template <int OF32>
__device__ __forceinline__ void gemm_body(const u16* __restrict__ A,
                                          const u16* __restrict__ Bw,
                                          const float* __restrict__ bias,
                                          void* __restrict__ Cout) {
  __shared__ __align__(16) char As[128 * 64];  // 128 rows x 32 bf16 (64B/row)
  __shared__ __align__(16) char Bs[128 * 64];

  const int tid = threadIdx.x;
  const int lane = tid & 63, w = tid >> 6;
  const int lr = lane & 15, lk = lane >> 4;
  const int m0 = blockIdx.y * 128, n0 = blockIdx.x * 128;
  const int wm = (w & 1) * 64, wn = (w >> 1) * 64;

  f32x4 acc[4][4];
#pragma unroll
  for (int i = 0; i < 4; i++)
#pragma unroll
    for (int j = 0; j < 4; j++) acc[i][j] = {0.f, 0.f, 0.f, 0.f};

  const char* Ab = (const char*)A;
  const char* Bb = (const char*)Bw;

  for (int k0 = 0; k0 < 2048; k0 += 32) {
    if (k0) __syncthreads();
#pragma unroll
    for (int j = 0; j < 2; j++) {
      const int o = j * 4096 + tid * 16;
      const int row = o >> 6, cb = o & 63;
      gload_lds16(Ab + (size_t)(m0 + row) * 4096 + k0 * 2 + cb, As + o);
      gload_lds16(Bb + (size_t)(n0 + row) * 4096 + k0 * 2 + cb, Bs + o);
    }
    __syncthreads();
    bf16x8 af[4], bfr[4];
#pragma unroll
    for (int i = 0; i < 4; i++)
      af[i] = *(const bf16x8*)(As + (wm + i * 16 + lr) * 64 + lk * 16);
#pragma unroll
    for (int j = 0; j < 4; j++)
      bfr[j] = *(const bf16x8*)(Bs + (wn + j * 16 + lr) * 64 + lk * 16);
#pragma unroll
    for (int i = 0; i < 4; i++)
#pragma unroll
      for (int j = 0; j < 4; j++)
        acc[i][j] =
            __builtin_amdgcn_mfma_f32_16x16x32_bf16(af[i], bfr[j], acc[i][j], 0, 0, 0);
  }

#pragma unroll
  for (int j = 0; j < 4; j++) {
    const int gcol = n0 + wn + j * 16 + lr;
    const float bv = bias[gcol];
#pragma unroll
    for (int i = 0; i < 4; i++) {
      const int grow = m0 + wm + i * 16 + lk * 4;
#pragma unroll
      for (int r = 0; r < 4; r++) {
        float v = acc[i][j][r] + bv;
        if (OF32)
          ((float*)Cout)[(size_t)(grow + r) * 2048 + gcol] = v;
        else
          ((u16*)Cout)[(size_t)(grow + r) * 2048 + gcol] = f2bf(v);
      }
    }
  }
}

__global__ __launch_bounds__(256) void qkv_kernel(
    const u16* __restrict__ hsb, const u16* __restrict__ wqb,
    const u16* __restrict__ wkb, const u16* __restrict__ wvb,
    const float* __restrict__ bq, const float* __restrict__ bk,
    const float* __restrict__ bv, u16* __restrict__ Qo, u16* __restrict__ Ko,
    u16* __restrict__ Vo) {
  const int z = blockIdx.z;
  const u16* Bw;
  const float* bias;
  u16* out;
  if (z == 0)      { Bw = wqb; bias = bq; out = Qo; }
  else if (z == 1) { Bw = wkb; bias = bk; out = Ko; }
  else             { Bw = wvb; bias = bv; out = Vo; }
  gemm_body<0>(hsb, Bw, bias, out);
}

__global__ __launch_bounds__(256) void oproj_kernel(const u16* __restrict__ ctx,
                                                    const u16* __restrict__ wob,
                                                    const float* __restrict__ bo,
                                                    float* __restrict__ out) {
  gemm_body<1>(ctx, wob, bo, out);
}

// ---------- fused causal attention with alibi + tanh cap ----------
// grid (32 qtiles, 64 bh), 256 threads = 4 waves, each wave owns 16 q-rows.
// tanh cap bounds scores to (-30,30) -> fixed-shift softmax p=exp(s-30),
// no online max / rescale needed.

__global__ __launch_bounds__(256) void attn_kernel(
    const u16* __restrict__ Qm, const u16* __restrict__ Km,
    const u16* __restrict__ Vm, const float* __restrict__ slopes,
    u16* __restrict__ ctx) {
  __shared__ __align__(16) char Ks[64 * 256];    // [kv][256B] xor-swizzled
  __shared__ __align__(16) char Vt[128 * 128];   // [d][128B]  xor-swizzled (V^T)
  __shared__ __align__(16) char Pb[4][16 * 128]; // per-wave P [16q][128B]

  const int qt = 31 - (int)blockIdx.x;  // longest blocks dispatch first
  const int bh = blockIdx.y;
  const int b = bh >> 4, h = bh & 15;
  const int tid = threadIdx.x;
  const int lane = tid & 63, w = tid >> 6;
  const int lr = lane & 15, lk = lane >> 4;

  const char* Qb = (const char*)Qm + (size_t)b * 2048 * 4096 + h * 256;
  const char* Kb = (const char*)Km + (size_t)b * 2048 * 4096 + h * 256;
  const char* Vb = (const char*)Vm + (size_t)b * 2048 * 4096 + h * 256;

  // Q fragments (A operand), rows q0+lr, k-chunks of 32
  const int q0 = qt * 64 + w * 16;
  bf16x8 qf[4];
#pragma unroll
  for (int kc = 0; kc < 4; kc++)
    qf[kc] = *(const bf16x8*)(Qb + (size_t)(q0 + lr) * 4096 + kc * 64 + lk * 16);

  const float slope = slopes[h];
  f32x4 pv[8];
#pragma unroll
  for (int i = 0; i < 8; i++) pv[i] = {0.f, 0.f, 0.f, 0.f};
  float rs[4] = {0.f, 0.f, 0.f, 0.f};

  for (int kvt = 0; kvt <= qt; kvt++) {
    __syncthreads();
    const int kv0 = kvt * 64;
    // stage K tile: linear LDS dest, pre-swizzled global source (m173 pattern)
#pragma unroll
    for (int j = 0; j < 4; j++) {
      const int o = j * 4096 + tid * 16;
      const int row = o >> 8;
      const int c = (o & 255) ^ ((row & 7) << 4);
      gload_lds16(Kb + (size_t)(kv0 + row) * 4096 + c, Ks + o);
    }
    // stage V transposed: reg-stage, swizzled ds_write_b32 (kv pairs)
#pragma unroll
    for (int it = 0; it < 2; it++) {
      const int item = it * 256 + tid;
      const int d0 = (item & 15) * 8;
      const int kv2 = item >> 4;
      const uint4 r0 = *(const uint4*)(Vb + (size_t)(kv0 + kv2 * 2) * 4096 + d0 * 2);
      const uint4 r1 = *(const uint4*)(Vb + (size_t)(kv0 + kv2 * 2 + 1) * 4096 + d0 * 2);
      const u32* p0 = (const u32*)&r0;
      const u32* p1 = (const u32*)&r1;
#pragma unroll
      for (int j = 0; j < 8; j++) {
        const u32 lo = (p0[j >> 1] >> ((j & 1) * 16)) & 0xffffu;
        const u32 hi = (p1[j >> 1] >> ((j & 1) * 16)) & 0xffffu;
        const int d = d0 + j;
        const int off = d * 128 + ((kv2 * 4) ^ (((d ^ (d >> 3)) & 7) << 4));
        *(u32*)(Vt + off) = lo | (hi << 16);
      }
    }
    __syncthreads();

    // S = Q K^T  (D rows = q, cols = kv)
    f32x4 sc[4];
#pragma unroll
    for (int nb = 0; nb < 4; nb++) {
      f32x4 a = {0.f, 0.f, 0.f, 0.f};
      const int krow = nb * 16 + lr;
#pragma unroll
      for (int kc = 0; kc < 4; kc++) {
        const int off = krow * 256 + ((kc * 64 + lk * 16) ^ ((krow & 7) << 4));
        bf16x8 kf = *(const bf16x8*)(Ks + off);
        a = __builtin_amdgcn_mfma_f32_16x16x32_bf16(qf[kc], kf, a, 0, 0, 0);
      }
      sc[nb] = a;
    }

    // alibi + scale + tanh cap + causal mask + fixed-shift exp; P -> LDS bf16
    const int diag = (kvt == qt);
#pragma unroll
    for (int nb = 0; nb < 4; nb++) {
      const int kv = kv0 + nb * 16 + lr;
#pragma unroll
      for (int r = 0; r < 4; r++) {
        const int q = qt * 64 + w * 16 + lk * 4 + r;
        float z = (sc[nb][r] + slope * (float)(kv - q)) * 0.08838834764831845f;
        // p = exp(30*tanh(z/30) - 30) = exp2(-86.5617.../(exp2(z*2*log2e/30)+1))
        float e2 = exp2f(z * 0.09617966939259756f);
        float p = exp2f(-86.56170245333781f * __builtin_amdgcn_rcpf(e2 + 1.0f));
        if (diag && (kv > q)) p = 0.0f;
        rs[r] += p;
        const int qq = lk * 4 + r;
        const int off = qq * 128 + (((nb * 16 + lr) * 2) ^ ((qq & 7) << 4));
        *(u16*)(Pb[w] + off) = f2bf(p);
      }
    }

    // ctx += P V   (A = P from LDS, B = V^T rows from LDS)
#pragma unroll
    for (int kc = 0; kc < 2; kc++) {
      const int poff = lr * 128 + ((kc * 64 + lk * 16) ^ ((lr & 7) << 4));
      bf16x8 pf = *(const bf16x8*)(Pb[w] + poff);
#pragma unroll
      for (int db = 0; db < 8; db++) {
        const int d = db * 16 + lr;
        const int voff = d * 128 + ((kc * 64 + lk * 16) ^ (((d ^ (d >> 3)) & 7) << 4));
        bf16x8 vf = *(const bf16x8*)(Vt + voff);
        pv[db] = __builtin_amdgcn_mfma_f32_16x16x32_bf16(pf, vf, pv[db], 0, 0, 0);
      }
    }
  }

  // row sums: reduce over the 16 lanes of each group, then normalize + store
#pragma unroll
  for (int r = 0; r < 4; r++) {
    float s = rs[r];
    s += __shfl_xor(s, 1);
    s += __shfl_xor(s, 2);
    s += __shfl_xor(s, 4);
    s += __shfl_xor(s, 8);
    rs[r] = 1.0f / s;
  }
  const size_t baserow = (size_t)b * 2048 + qt * 64 + w * 16;
#pragma unroll
  for (int db = 0; db < 8; db++) {
#pragma unroll
    for (int r = 0; r < 4; r++) {
      const float v = pv[db][r] * rs[r];
      const size_t row = baserow + lk * 4 + r;
      ctx[row * 2048 + h * 128 + db * 16 + lr] = f2bf(v);
    }
  }
}

// ---------- launcher ----------

extern "C" void kernel_launch(void* const* d_in, const int* in_sizes, int n_in,
                              void* d_out, int out_size, void* d_ws,
                              size_t ws_size, hipStream_t stream) {
  const float* hs = (const float*)d_in[0];
  const float* Wq = (const float*)d_in[1];
  const float* bq = (const float*)d_in[2];
  const float* Wk = (const float*)d_in[3];
  const float* bk = (const float*)d_in[4];
  const float* Wv = (const float*)d_in[5];
  const float* bv = (const float*)d_in[6];
  const float* Wo = (const float*)d_in[7];
  const float* bo = (const float*)d_in[8];
  const float* slopes = (const float*)d_in[9];

  char* ws = (char*)d_ws;
  u16* hsb = (u16*)(ws);                 // 33.5 MB, reused as ctx after QKV
  u16* wqb = (u16*)(ws + 33554432);
  u16* wkb = (u16*)(ws + 41943040);
  u16* wvb = (u16*)(ws + 50331648);
  u16* wob = (u16*)(ws + 58720256);
  u16* Qb  = (u16*)(ws + 67108864);
  u16* Kb  = (u16*)(ws + 100663296);
  u16* Vb  = (u16*)(ws + 134217728);
  u16* ctxb = hsb;  // alias: hs_bf16 dead after QKV GEMM

  convert_kernel<<<16384, 256, 0, stream>>>(hs, Wq, Wk, Wv, Wo, hsb, wqb, wkb,
                                            wvb, wob);
  qkv_kernel<<<dim3(16, 64, 3), 256, 0, stream>>>(hsb, wqb, wkb, wvb, bq, bk,
                                                  bv, Qb, Kb, Vb);
  attn_kernel<<<dim3(32, 64), 256, 0, stream>>>(Qb, Kb, Vb, slopes, ctxb);
  oproj_kernel<<<dim3(16, 64), 256, 0, stream>>>(ctxb, wob, bo, (float*)d_out);
}

// Round 2
// 572.604 us; speedup vs baseline: 1.2434x; 1.2434x over previous
//
#include <hip/hip_runtime.h>

typedef unsigned int u32;
typedef unsigned short u16;
typedef __bf16 bf16x8 __attribute__((ext_vector_type(8)));
typedef float f32x4 __attribute__((ext_vector_type(4)));

// ---------- helpers ----------

__device__ __forceinline__ u16 f2bf(float f) {
  u32 u = __builtin_bit_cast(u32, f);
  u32 r = u + 0x7fffu + ((u >> 16) & 1u);  // RNE
  return (u16)(r >> 16);
}

__device__ __forceinline__ void gload_lds16(const void* g, void* l) {
  __builtin_amdgcn_global_load_lds(
      (__attribute__((address_space(1))) void*)(g),
      (__attribute__((address_space(3))) void*)(l), 16, 0, 0);
}

// ---------- fp32 -> bf16 conversion (hs + 4 weights) ----------

__global__ __launch_bounds__(256) void convert_kernel(
    const float* __restrict__ hs, const float* __restrict__ wq,
    const float* __restrict__ wk, const float* __restrict__ wv,
    const float* __restrict__ wo,
    u16* __restrict__ hsb, u16* __restrict__ wqb, u16* __restrict__ wkb,
    u16* __restrict__ wvb, u16* __restrict__ wob) {
  long t = (long)blockIdx.x * 256 + threadIdx.x;
  const float* src;
  u16* dst;
  long off;
  if (t < 2097152) {
    src = hs; dst = hsb; off = t << 3;
  } else {
    long u = t - 2097152;
    int wi = (int)(u >> 19);
    off = (u & 524287) << 3;
    if (wi == 0)      { src = wq; dst = wqb; }
    else if (wi == 1) { src = wk; dst = wkb; }
    else if (wi == 2) { src = wv; dst = wvb; }
    else              { src = wo; dst = wob; }
  }
  float4 a = *(const float4*)(src + off);
  float4 b = *(const float4*)(src + off + 4);
  uint4 o;
  o.x = (u32)f2bf(a.x) | ((u32)f2bf(a.y) << 16);
  o.y = (u32)f2bf(a.z) | ((u32)f2bf(a.w) << 16);
  o.z = (u32)f2bf(b.x) | ((u32)f2bf(b.y) << 16);
  o.w = (u32)f2bf(b.z) | ((u32)f2bf(b.w) << 16);
  *(uint4*)(dst + off) = o;
}

// ---------- GEMM C[8192x2048] = A[8192x2048] * B[2048x2048]^T + bias ----------

template <int OF32>
__device__ __forceinline__ void gemm_body(const u16* __restrict__ A,
                                          const u16* __restrict__ Bw,
                                          const float* __restrict__ bias,
                                          void* __restrict__ Cout) {
  __shared__ __align__(16) char As[128 * 64];
  __shared__ __align__(16) char Bs[128 * 64];

  const int tid = threadIdx.x;
  const int lane = tid & 63, w = tid >> 6;
  const int lr = lane & 15, lk = lane >> 4;
  const int m0 = blockIdx.y * 128, n0 = blockIdx.x * 128;
  const int wm = (w & 1) * 64, wn = (w >> 1) * 64;

  f32x4 acc[4][4];
#pragma unroll
  for (int i = 0; i < 4; i++)
#pragma unroll
    for (int j = 0; j < 4; j++) acc[i][j] = {0.f, 0.f, 0.f, 0.f};

  const char* Ab = (const char*)A;
  const char* Bb = (const char*)Bw;

  for (int k0 = 0; k0 < 2048; k0 += 32) {
    if (k0) __syncthreads();
#pragma unroll
    for (int j = 0; j < 2; j++) {
      const int o = j * 4096 + tid * 16;
      const int row = o >> 6, cb = o & 63;
      gload_lds16(Ab + (size_t)(m0 + row) * 4096 + k0 * 2 + cb, As + o);
      gload_lds16(Bb + (size_t)(n0 + row) * 4096 + k0 * 2 + cb, Bs + o);
    }
    __syncthreads();
    bf16x8 af[4], bfr[4];
#pragma unroll
    for (int i = 0; i < 4; i++)
      af[i] = *(const bf16x8*)(As + (wm + i * 16 + lr) * 64 + lk * 16);
#pragma unroll
    for (int j = 0; j < 4; j++)
      bfr[j] = *(const bf16x8*)(Bs + (wn + j * 16 + lr) * 64 + lk * 16);
#pragma unroll
    for (int i = 0; i < 4; i++)
#pragma unroll
      for (int j = 0; j < 4; j++)
        acc[i][j] =
            __builtin_amdgcn_mfma_f32_16x16x32_bf16(af[i], bfr[j], acc[i][j], 0, 0, 0);
  }

#pragma unroll
  for (int j = 0; j < 4; j++) {
    const int gcol = n0 + wn + j * 16 + lr;
    const float bv = bias[gcol];
#pragma unroll
    for (int i = 0; i < 4; i++) {
      const int grow = m0 + wm + i * 16 + lk * 4;
#pragma unroll
      for (int r = 0; r < 4; r++) {
        float v = acc[i][j][r] + bv;
        if (OF32)
          ((float*)Cout)[(size_t)(grow + r) * 2048 + gcol] = v;
        else
          ((u16*)Cout)[(size_t)(grow + r) * 2048 + gcol] = f2bf(v);
      }
    }
  }
}

__global__ __launch_bounds__(256) void qkv_kernel(
    const u16* __restrict__ hsb, const u16* __restrict__ wqb,
    const u16* __restrict__ wkb, const u16* __restrict__ wvb,
    const float* __restrict__ bq, const float* __restrict__ bk,
    const float* __restrict__ bv, u16* __restrict__ Qo, u16* __restrict__ Ko,
    u16* __restrict__ Vo) {
  const int z = blockIdx.z;
  const u16* Bw;
  const float* bias;
  u16* out;
  if (z == 0)      { Bw = wqb; bias = bq; out = Qo; }
  else if (z == 1) { Bw = wkb; bias = bk; out = Ko; }
  else             { Bw = wvb; bias = bv; out = Vo; }
  gemm_body<0>(hsb, Bw, bias, out);
}

__global__ __launch_bounds__(256) void oproj_kernel(const u16* __restrict__ ctx,
                                                    const u16* __restrict__ wob,
                                                    const float* __restrict__ bo,
                                                    float* __restrict__ out) {
  gemm_body<1>(ctx, wob, bo, out);
}

// ---------- fused causal attention with alibi + tanh cap ----------
// 512 blocks (1D), 512 threads = 8 waves. Each block owns Q-supertile pair
// (pi, 15-pi) of 128 rows each -> exactly 34 kv-tile iterations per block
// (perfect balance, 2 blocks/CU all-resident). Pipelined staging: K via
// global_load_lds into double-buffered Ks; V reg-staged one iter ahead,
// transposed ds_write into double-buffered Vt. One barrier per iteration.

__global__ __launch_bounds__(512, 2) void attn_kernel(
    const u16* __restrict__ Qm, const u16* __restrict__ Km,
    const u16* __restrict__ Vm, const float* __restrict__ slopes,
    u16* __restrict__ ctx) {
  __shared__ __align__(16) char Ks[2][64 * 256];   // 32 KB, xor-swizzled rows
  __shared__ __align__(16) char Vt[2][128 * 128];  // 32 KB, V^T xor-swizzled
  __shared__ __align__(16) char Pb[8][16 * 128];   // 16 KB, per-wave P

  const int bid = blockIdx.x;                       // 0..511
  const int sw = (bid & 7) * 64 + (bid >> 3);       // XCD-contiguous heads
  const int bh = sw >> 3, pi = sw & 7;
  const int b = bh >> 4, h = bh & 15;
  const int NTA = 2 * pi + 2;                       // tiles for supertile A

  const int tid = threadIdx.x;
  const int lane = tid & 63, w = tid >> 6;
  const int lr = lane & 15, lk = lane >> 4;

  const char* Qb = (const char*)Qm + (size_t)b * 2048 * 4096 + h * 256;
  const char* Kb = (const char*)Km + (size_t)b * 2048 * 4096 + h * 256;
  const char* Vb = (const char*)Vm + (size_t)b * 2048 * 4096 + h * 256;
  const float slope = slopes[h];

  const int vd0 = (tid & 15) * 8;  // V staging: d block
  const int vkv2 = tid >> 4;       // V staging: kv pair 0..31

  uint4 vr0, vr1;

  auto kvt_of = [&](int it) { return it < NTA ? it : it - NTA; };

  auto stageK = [&](int it, int bufi) {
    const int kv0 = kvt_of(it) * 64;
#pragma unroll
    for (int j = 0; j < 2; j++) {
      const int o = j * 8192 + tid * 16;
      const int row = o >> 8, c = (o & 255) ^ ((row & 7) << 4);
      gload_lds16(Kb + (size_t)(kv0 + row) * 4096 + c, Ks[bufi] + o);
    }
  };
  auto loadV = [&](int it) {
    const int kv0 = kvt_of(it) * 64;
    vr0 = *(const uint4*)(Vb + (size_t)(kv0 + vkv2 * 2) * 4096 + vd0 * 2);
    vr1 = *(const uint4*)(Vb + (size_t)(kv0 + vkv2 * 2 + 1) * 4096 + vd0 * 2);
  };
  auto writeV = [&](int bufi) {
    const u32* p0 = (const u32*)&vr0;
    const u32* p1 = (const u32*)&vr1;
#pragma unroll
    for (int j = 0; j < 8; j++) {
      const u32 lo = (p0[j >> 1] >> ((j & 1) * 16)) & 0xffffu;
      const u32 hi = (p1[j >> 1] >> ((j & 1) * 16)) & 0xffffu;
      const int d = vd0 + j;
      const int off = d * 128 + ((vkv2 * 4) ^ (((d ^ (d >> 3)) & 7) << 4));
      *(u32*)(Vt[bufi] + off) = lo | (hi << 16);
    }
  };

  bf16x8 qf[4];
  f32x4 pv[8];
  float rs[4];
  int q0 = 0;

  stageK(0, 0);
  loadV(0);

  for (int it = 0; it < 34; ++it) {
    const int bufi = it & 1;
    const int kv0 = kvt_of(it) * 64;

    if (it == 0 || it == NTA) {  // block-uniform: (re)load Q, reset acc
      const int st = (it == 0) ? pi : (15 - pi);
      q0 = st * 128 + w * 16;
#pragma unroll
      for (int kc = 0; kc < 4; kc++)
        qf[kc] =
            *(const bf16x8*)(Qb + (size_t)(q0 + lr) * 4096 + kc * 64 + lk * 16);
#pragma unroll
      for (int i = 0; i < 8; i++) pv[i] = {0.f, 0.f, 0.f, 0.f};
      rs[0] = rs[1] = rs[2] = rs[3] = 0.f;
    }

    writeV(bufi);      // V(it) regs -> Vt[bufi] (waits on in-flight loads)
    __syncthreads();   // Ks[bufi]+Vt[bufi] visible; prev-iter reads all done
    if (it + 1 < 34) { // prefetch next tile (hidden under compute below)
      stageK(it + 1, bufi ^ 1);
      loadV(it + 1);
    }

    // S = Q K^T
    f32x4 sc[4];
    __builtin_amdgcn_s_setprio(1);
#pragma unroll
    for (int nb = 0; nb < 4; nb++) {
      f32x4 a = {0.f, 0.f, 0.f, 0.f};
      const int krow = nb * 16 + lr;
#pragma unroll
      for (int kc = 0; kc < 4; kc++) {
        const int off = krow * 256 + ((kc * 64 + lk * 16) ^ ((krow & 7) << 4));
        bf16x8 kf = *(const bf16x8*)(Ks[bufi] + off);
        a = __builtin_amdgcn_mfma_f32_16x16x32_bf16(qf[kc], kf, a, 0, 0, 0);
      }
      sc[nb] = a;
    }
    __builtin_amdgcn_s_setprio(0);

    // alibi + scale + tanh cap + causal mask + fixed-shift exp; P -> LDS bf16
#pragma unroll
    for (int nb = 0; nb < 4; nb++) {
      const int kv = kv0 + nb * 16 + lr;
#pragma unroll
      for (int r = 0; r < 4; r++) {
        const int q = q0 + lk * 4 + r;
        float z = (sc[nb][r] + slope * (float)(kv - q)) * 0.08838834764831845f;
        float e2 = exp2f(z * 0.09617966939259756f);
        float p = exp2f(-86.56170245333781f * __builtin_amdgcn_rcpf(e2 + 1.0f));
        p = (kv <= q) ? p : 0.0f;
        rs[r] += p;
        const int qq = lk * 4 + r;
        const int off = qq * 128 + (((nb * 16 + lr) * 2) ^ ((qq & 7) << 4));
        *(u16*)(Pb[w] + off) = f2bf(p);
      }
    }

    // ctx += P V
    __builtin_amdgcn_s_setprio(1);
#pragma unroll
    for (int kc = 0; kc < 2; kc++) {
      const int poff = lr * 128 + ((kc * 64 + lk * 16) ^ ((lr & 7) << 4));
      bf16x8 pf = *(const bf16x8*)(Pb[w] + poff);
#pragma unroll
      for (int db = 0; db < 8; db++) {
        const int d = db * 16 + lr;
        const int voff =
            d * 128 + ((kc * 64 + lk * 16) ^ (((d ^ (d >> 3)) & 7) << 4));
        bf16x8 vf = *(const bf16x8*)(Vt[bufi] + voff);
        pv[db] = __builtin_amdgcn_mfma_f32_16x16x32_bf16(pf, vf, pv[db], 0, 0, 0);
      }
    }
    __builtin_amdgcn_s_setprio(0);

    if (it == NTA - 1 || it == 33) {  // finalize current supertile
      float inv[4];
#pragma unroll
      for (int r = 0; r < 4; r++) {
        float s = rs[r];
        s += __shfl_xor(s, 1);
        s += __shfl_xor(s, 2);
        s += __shfl_xor(s, 4);
        s += __shfl_xor(s, 8);
        inv[r] = 1.0f / s;
      }
      const size_t baserow = (size_t)b * 2048 + q0 + lk * 4;
#pragma unroll
      for (int db = 0; db < 8; db++)
#pragma unroll
        for (int r = 0; r < 4; r++)
          ctx[(baserow + r) * 2048 + h * 128 + db * 16 + lr] =
              f2bf(pv[db][r] * inv[r]);
    }
  }
}

// ---------- launcher ----------

extern "C" void kernel_launch(void* const* d_in, const int* in_sizes, int n_in,
                              void* d_out, int out_size, void* d_ws,
                              size_t ws_size, hipStream_t stream) {
  const float* hs = (const float*)d_in[0];
  const float* Wq = (const float*)d_in[1];
  const float* bq = (const float*)d_in[2];
  const float* Wk = (const float*)d_in[3];
  const float* bk = (const float*)d_in[4];
  const float* Wv = (const float*)d_in[5];
  const float* bv = (const float*)d_in[6];
  const float* Wo = (const float*)d_in[7];
  const float* bo = (const float*)d_in[8];
  const float* slopes = (const float*)d_in[9];

  char* ws = (char*)d_ws;
  u16* hsb = (u16*)(ws);                 // 33.5 MB, reused as ctx after QKV
  u16* wqb = (u16*)(ws + 33554432);
  u16* wkb = (u16*)(ws + 41943040);
  u16* wvb = (u16*)(ws + 50331648);
  u16* wob = (u16*)(ws + 58720256);
  u16* Qb  = (u16*)(ws + 67108864);
  u16* Kb  = (u16*)(ws + 100663296);
  u16* Vb  = (u16*)(ws + 134217728);
  u16* ctxb = hsb;  // alias: hs_bf16 dead after QKV GEMM

  convert_kernel<<<16384, 256, 0, stream>>>(hs, Wq, Wk, Wv, Wo, hsb, wqb, wkb,
                                            wvb, wob);
  qkv_kernel<<<dim3(16, 64, 3), 256, 0, stream>>>(hsb, wqb, wkb, wvb, bq, bk,
                                                  bv, Qb, Kb, Vb);
  attn_kernel<<<512, 512, 0, stream>>>(Qb, Kb, Vb, slopes, ctxb);
  oproj_kernel<<<dim3(16, 64), 256, 0, stream>>>(ctxb, wob, bo, (float*)d_out);
}

// Round 3
// 532.778 us; speedup vs baseline: 1.3363x; 1.0748x over previous
//
#include <hip/hip_runtime.h>

typedef unsigned int u32;
typedef unsigned short u16;
typedef __bf16 bf16x8 __attribute__((ext_vector_type(8)));
typedef float f32x4 __attribute__((ext_vector_type(4)));

// ---------- helpers ----------

__device__ __forceinline__ u16 f2bf(float f) {
  u32 u = __builtin_bit_cast(u32, f);
  u32 r = u + 0x7fffu + ((u >> 16) & 1u);  // RNE
  return (u16)(r >> 16);
}

__device__ __forceinline__ void gload_lds16(const void* g, void* l) {
  __builtin_amdgcn_global_load_lds(
      (__attribute__((address_space(1))) void*)(g),
      (__attribute__((address_space(3))) void*)(l), 16, 0, 0);
}

// ---------- fp32 -> bf16 conversion (hs + 4 weights) ----------

__global__ __launch_bounds__(256) void convert_kernel(
    const float* __restrict__ hs, const float* __restrict__ wq,
    const float* __restrict__ wk, const float* __restrict__ wv,
    const float* __restrict__ wo,
    u16* __restrict__ hsb, u16* __restrict__ wqb, u16* __restrict__ wkb,
    u16* __restrict__ wvb, u16* __restrict__ wob) {
  long t = (long)blockIdx.x * 256 + threadIdx.x;
  const float* src;
  u16* dst;
  long off;
  if (t < 2097152) {
    src = hs; dst = hsb; off = t << 3;
  } else {
    long u = t - 2097152;
    int wi = (int)(u >> 19);
    off = (u & 524287) << 3;
    if (wi == 0)      { src = wq; dst = wqb; }
    else if (wi == 1) { src = wk; dst = wkb; }
    else if (wi == 2) { src = wv; dst = wvb; }
    else              { src = wo; dst = wob; }
  }
  float4 a = *(const float4*)(src + off);
  float4 b = *(const float4*)(src + off + 4);
  uint4 o;
  o.x = (u32)f2bf(a.x) | ((u32)f2bf(a.y) << 16);
  o.y = (u32)f2bf(a.z) | ((u32)f2bf(a.w) << 16);
  o.z = (u32)f2bf(b.x) | ((u32)f2bf(b.y) << 16);
  o.w = (u32)f2bf(b.z) | ((u32)f2bf(b.w) << 16);
  *(uint4*)(dst + off) = o;
}

// ---------- 256x256 phase-split GEMM, BK=64, 8 waves, K=2048 ----------
// C[M x n_tiles*256] = A[M x 2048] * B[n x 2048]^T (+bias). Deep pipeline:
// LDS = 2 buf x {A,B} x {khalf0,khalf1} slots (8 x 16KB). Per K-tile: 4
// phases, each {stage 1 half-tile (t+1/t+2) | ds_read subtile | s_barrier |
// 16 MFMA | s_barrier}; counted vmcnt(4) once per tile (never 0). A k-half
// slot is dead after its read phase's closing barrier, so staging t+2's
// khalf0 into the live buffer at phase 3/4 is race-free. Tail stages clamp
// to the last tile (value-identical rewrite -> benign; uniform vmcnt).

template <int OF32>
__global__ __launch_bounds__(512, 2) void gemm256_kernel(
    const u16* __restrict__ A, const u16* __restrict__ Bw,
    const float* __restrict__ bias0, const float* __restrict__ bias1,
    const float* __restrict__ bias2, void* __restrict__ o0,
    void* __restrict__ o1, void* __restrict__ o2, int m_tiles, int n_tiles) {
  __shared__ __align__(16) char L[2][2][2][16384];  // [buf][op][khalf]

  const int tid = threadIdx.x;
  const int lane = tid & 63, w = tid >> 6;
  const int lr = lane & 15, lk = lane >> 4;
  const int wm = (w >> 2) * 128, wn = (w & 3) * 64;

  // XCD-aware mapping: each XCD owns n_tiles/8 B-panels (L2-resident)
  const int bid = blockIdx.x;
  const int xcd = bid & 7, loc = bid >> 3;
  const int n_idx = xcd * (n_tiles >> 3) + loc / m_tiles;
  const int m_idx = loc % m_tiles;
  const int m0 = m_idx * 256, n0 = n_idx * 256;

  const char* Ab = (const char*)A;
  const char* Bb = (const char*)Bw;

  auto stage = [&](int t, int kh, int isB) {
    const char* G = isB ? Bb : Ab;
    const int r0 = isB ? n0 : m0;
    char* Ld = &L[t & 1][isB][kh][0];
    const size_t kb = (size_t)(t * 64 + kh * 32) * 2;
#pragma unroll
    for (int j = 0; j < 2; j++) {
      const int o = j * 8192 + tid * 16;
      const int row = o >> 6;
      const int c = (o & 63) ^ (((row >> 1) & 3) << 4);
      gload_lds16(G + (size_t)(r0 + row) * 4096 + kb + c, Ld + o);
    }
  };
  auto rdA = [&](bf16x8* dst, int buf, int kh, int mset) {
#pragma unroll
    for (int m = 0; m < 4; m++) {
      const int row = wm + mset * 64 + m * 16 + lr;
      const int c = (lk * 16) ^ (((row >> 1) & 3) << 4);
      dst[m] = *(const bf16x8*)(&L[buf][0][kh][0] + row * 64 + c);
    }
  };
  auto rdB = [&](bf16x8* dst, int buf, int kh) {
#pragma unroll
    for (int n = 0; n < 4; n++) {
      const int row = wn + n * 16 + lr;
      const int c = (lk * 16) ^ (((row >> 1) & 3) << 4);
      dst[n] = *(const bf16x8*)(&L[buf][1][kh][0] + row * 64 + c);
    }
  };

  f32x4 acc[2][4][4];
#pragma unroll
  for (int s = 0; s < 2; s++)
#pragma unroll
    for (int m = 0; m < 4; m++)
#pragma unroll
      for (int n = 0; n < 4; n++) acc[s][m][n] = {0.f, 0.f, 0.f, 0.f};

  auto mm = [&](f32x4 (&ac)[4][4], bf16x8* a_, bf16x8* b_) {
    __builtin_amdgcn_s_setprio(1);
#pragma unroll
    for (int m = 0; m < 4; m++)
#pragma unroll
      for (int n = 0; n < 4; n++)
        ac[m][n] = __builtin_amdgcn_mfma_f32_16x16x32_bf16(a_[m], b_[n],
                                                           ac[m][n], 0, 0, 0);
    __builtin_amdgcn_s_setprio(0);
  };

  // prologue: t0 fully + t1 khalf0; leave t1.{Akh0,Bkh0} in flight
  stage(0, 0, 0); stage(0, 0, 1); stage(0, 1, 0); stage(0, 1, 1);
  stage(1, 0, 0); stage(1, 0, 1);
  asm volatile("s_waitcnt vmcnt(4)" ::: "memory");
  asm volatile("s_barrier" ::: "memory");

  bf16x8 af[4], af2[4], bf[4];
  for (int t = 0; t < 32; ++t) {
    const int buf = t & 1;
    const int t1 = (t + 1 < 32) ? t + 1 : 31;
    const int t2 = (t + 2 < 32) ? t + 2 : 31;
    // phase 1: khalf0, M-frags 0-3
    stage(t1, 1, 0);
    rdA(af, buf, 0, 0); rdB(bf, buf, 0);
    asm volatile("s_barrier" ::: "memory");
    mm(acc[0], af, bf);
    asm volatile("s_barrier" ::: "memory");
    // phase 2: khalf0, M-frags 4-7
    stage(t1, 1, 1);
    rdA(af2, buf, 0, 1);
    asm volatile("s_barrier" ::: "memory");
    mm(acc[1], af2, bf);
    asm volatile("s_barrier" ::: "memory");
    // phase 3: khalf1, M-frags 0-3
    stage(t2, 0, 0);
    rdA(af, buf, 1, 0); rdB(bf, buf, 1);
    asm volatile("s_barrier" ::: "memory");
    mm(acc[0], af, bf);
    asm volatile("s_barrier" ::: "memory");
    // phase 4: khalf1, M-frags 4-7
    stage(t2, 0, 1);
    rdA(af2, buf, 1, 1);
    asm volatile("s_barrier" ::: "memory");
    mm(acc[1], af2, bf);
    asm volatile("s_waitcnt vmcnt(4)" ::: "memory");
    asm volatile("s_barrier" ::: "memory");
  }
  asm volatile("s_waitcnt vmcnt(0)" ::: "memory");

  // epilogue: bias + store
  const float* bias;
  void* op;
  int nl0;
  if (OF32) {
    bias = bias0; op = o0; nl0 = n0;
  } else {
    const int seg = n0 >> 11;
    bias = seg == 0 ? bias0 : (seg == 1 ? bias1 : bias2);
    op = seg == 0 ? o0 : (seg == 1 ? o1 : o2);
    nl0 = n0 & 2047;
  }
#pragma unroll
  for (int n = 0; n < 4; n++) {
    const int col = nl0 + wn + n * 16 + lr;
    const float bv = bias[col];
#pragma unroll
    for (int s = 0; s < 2; s++)
#pragma unroll
      for (int m = 0; m < 4; m++) {
        const int grow = m0 + wm + s * 64 + m * 16 + lk * 4;
#pragma unroll
        for (int r = 0; r < 4; r++) {
          const float v = acc[s][m][n][r] + bv;
          if (OF32)
            ((float*)op)[(size_t)(grow + r) * 2048 + col] = v;
          else
            ((u16*)op)[(size_t)(grow + r) * 2048 + col] = f2bf(v);
        }
      }
  }
}

// ---------- fused causal attention with alibi + tanh cap ----------
// (unchanged from round 2)

__global__ __launch_bounds__(512, 2) void attn_kernel(
    const u16* __restrict__ Qm, const u16* __restrict__ Km,
    const u16* __restrict__ Vm, const float* __restrict__ slopes,
    u16* __restrict__ ctx) {
  __shared__ __align__(16) char Ks[2][64 * 256];
  __shared__ __align__(16) char Vt[2][128 * 128];
  __shared__ __align__(16) char Pb[8][16 * 128];

  const int bid = blockIdx.x;
  const int sw = (bid & 7) * 64 + (bid >> 3);
  const int bh = sw >> 3, pi = sw & 7;
  const int b = bh >> 4, h = bh & 15;
  const int NTA = 2 * pi + 2;

  const int tid = threadIdx.x;
  const int lane = tid & 63, w = tid >> 6;
  const int lr = lane & 15, lk = lane >> 4;

  const char* Qb = (const char*)Qm + (size_t)b * 2048 * 4096 + h * 256;
  const char* Kb = (const char*)Km + (size_t)b * 2048 * 4096 + h * 256;
  const char* Vb = (const char*)Vm + (size_t)b * 2048 * 4096 + h * 256;
  const float slope = slopes[h];

  const int vd0 = (tid & 15) * 8;
  const int vkv2 = tid >> 4;

  uint4 vr0, vr1;

  auto kvt_of = [&](int it) { return it < NTA ? it : it - NTA; };

  auto stageK = [&](int it, int bufi) {
    const int kv0 = kvt_of(it) * 64;
#pragma unroll
    for (int j = 0; j < 2; j++) {
      const int o = j * 8192 + tid * 16;
      const int row = o >> 8, c = (o & 255) ^ ((row & 7) << 4);
      gload_lds16(Kb + (size_t)(kv0 + row) * 4096 + c, Ks[bufi] + o);
    }
  };
  auto loadV = [&](int it) {
    const int kv0 = kvt_of(it) * 64;
    vr0 = *(const uint4*)(Vb + (size_t)(kv0 + vkv2 * 2) * 4096 + vd0 * 2);
    vr1 = *(const uint4*)(Vb + (size_t)(kv0 + vkv2 * 2 + 1) * 4096 + vd0 * 2);
  };
  auto writeV = [&](int bufi) {
    const u32* p0 = (const u32*)&vr0;
    const u32* p1 = (const u32*)&vr1;
#pragma unroll
    for (int j = 0; j < 8; j++) {
      const u32 lo = (p0[j >> 1] >> ((j & 1) * 16)) & 0xffffu;
      const u32 hi = (p1[j >> 1] >> ((j & 1) * 16)) & 0xffffu;
      const int d = vd0 + j;
      const int off = d * 128 + ((vkv2 * 4) ^ (((d ^ (d >> 3)) & 7) << 4));
      *(u32*)(Vt[bufi] + off) = lo | (hi << 16);
    }
  };

  bf16x8 qf[4];
  f32x4 pv[8];
  float rs[4];
  int q0 = 0;

  stageK(0, 0);
  loadV(0);

  for (int it = 0; it < 34; ++it) {
    const int bufi = it & 1;
    const int kv0 = kvt_of(it) * 64;

    if (it == 0 || it == NTA) {
      const int st = (it == 0) ? pi : (15 - pi);
      q0 = st * 128 + w * 16;
#pragma unroll
      for (int kc = 0; kc < 4; kc++)
        qf[kc] =
            *(const bf16x8*)(Qb + (size_t)(q0 + lr) * 4096 + kc * 64 + lk * 16);
#pragma unroll
      for (int i = 0; i < 8; i++) pv[i] = {0.f, 0.f, 0.f, 0.f};
      rs[0] = rs[1] = rs[2] = rs[3] = 0.f;
    }

    writeV(bufi);
    __syncthreads();
    if (it + 1 < 34) {
      stageK(it + 1, bufi ^ 1);
      loadV(it + 1);
    }

    f32x4 sc[4];
    __builtin_amdgcn_s_setprio(1);
#pragma unroll
    for (int nb = 0; nb < 4; nb++) {
      f32x4 a = {0.f, 0.f, 0.f, 0.f};
      const int krow = nb * 16 + lr;
#pragma unroll
      for (int kc = 0; kc < 4; kc++) {
        const int off = krow * 256 + ((kc * 64 + lk * 16) ^ ((krow & 7) << 4));
        bf16x8 kf = *(const bf16x8*)(Ks[bufi] + off);
        a = __builtin_amdgcn_mfma_f32_16x16x32_bf16(qf[kc], kf, a, 0, 0, 0);
      }
      sc[nb] = a;
    }
    __builtin_amdgcn_s_setprio(0);

#pragma unroll
    for (int nb = 0; nb < 4; nb++) {
      const int kv = kv0 + nb * 16 + lr;
#pragma unroll
      for (int r = 0; r < 4; r++) {
        const int q = q0 + lk * 4 + r;
        float z = (sc[nb][r] + slope * (float)(kv - q)) * 0.08838834764831845f;
        float e2 = exp2f(z * 0.09617966939259756f);
        float p = exp2f(-86.56170245333781f * __builtin_amdgcn_rcpf(e2 + 1.0f));
        p = (kv <= q) ? p : 0.0f;
        rs[r] += p;
        const int qq = lk * 4 + r;
        const int off = qq * 128 + (((nb * 16 + lr) * 2) ^ ((qq & 7) << 4));
        *(u16*)(Pb[w] + off) = f2bf(p);
      }
    }

    __builtin_amdgcn_s_setprio(1);
#pragma unroll
    for (int kc = 0; kc < 2; kc++) {
      const int poff = lr * 128 + ((kc * 64 + lk * 16) ^ ((lr & 7) << 4));
      bf16x8 pf = *(const bf16x8*)(Pb[w] + poff);
#pragma unroll
      for (int db = 0; db < 8; db++) {
        const int d = db * 16 + lr;
        const int voff =
            d * 128 + ((kc * 64 + lk * 16) ^ (((d ^ (d >> 3)) & 7) << 4));
        bf16x8 vf = *(const bf16x8*)(Vt[bufi] + voff);
        pv[db] = __builtin_amdgcn_mfma_f32_16x16x32_bf16(pf, vf, pv[db], 0, 0, 0);
      }
    }
    __builtin_amdgcn_s_setprio(0);

    if (it == NTA - 1 || it == 33) {
      float inv[4];
#pragma unroll
      for (int r = 0; r < 4; r++) {
        float s = rs[r];
        s += __shfl_xor(s, 1);
        s += __shfl_xor(s, 2);
        s += __shfl_xor(s, 4);
        s += __shfl_xor(s, 8);
        inv[r] = 1.0f / s;
      }
      const size_t baserow = (size_t)b * 2048 + q0 + lk * 4;
#pragma unroll
      for (int db = 0; db < 8; db++)
#pragma unroll
        for (int r = 0; r < 4; r++)
          ctx[(baserow + r) * 2048 + h * 128 + db * 16 + lr] =
              f2bf(pv[db][r] * inv[r]);
    }
  }
}

// ---------- launcher ----------

extern "C" void kernel_launch(void* const* d_in, const int* in_sizes, int n_in,
                              void* d_out, int out_size, void* d_ws,
                              size_t ws_size, hipStream_t stream) {
  const float* hs = (const float*)d_in[0];
  const float* Wq = (const float*)d_in[1];
  const float* bq = (const float*)d_in[2];
  const float* Wk = (const float*)d_in[3];
  const float* bk = (const float*)d_in[4];
  const float* Wv = (const float*)d_in[5];
  const float* bv = (const float*)d_in[6];
  const float* Wo = (const float*)d_in[7];
  const float* bo = (const float*)d_in[8];
  const float* slopes = (const float*)d_in[9];

  char* ws = (char*)d_ws;
  u16* hsb = (u16*)(ws);                 // reused as ctx after QKV
  u16* wqb = (u16*)(ws + 33554432);      // wq|wk|wv contiguous => [6144][2048]
  u16* wkb = (u16*)(ws + 41943040);
  u16* wvb = (u16*)(ws + 50331648);
  u16* wob = (u16*)(ws + 58720256);
  u16* Qb  = (u16*)(ws + 67108864);
  u16* Kb  = (u16*)(ws + 100663296);
  u16* Vb  = (u16*)(ws + 134217728);
  u16* ctxb = hsb;

  convert_kernel<<<16384, 256, 0, stream>>>(hs, Wq, Wk, Wv, Wo, hsb, wqb, wkb,
                                            wvb, wob);
  // fused QKV: M=8192, N=6144, K=2048 -> 32 m-tiles x 24 n-tiles = 768 blocks
  gemm256_kernel<0><<<768, 512, 0, stream>>>(hsb, wqb, bq, bk, bv, Qb, Kb, Vb,
                                             32, 24);
  attn_kernel<<<512, 512, 0, stream>>>(Qb, Kb, Vb, slopes, ctxb);
  // oproj: M=8192, N=2048 -> 32 x 8 = 256 blocks (1/CU, each XCD one B-panel)
  gemm256_kernel<1><<<256, 512, 0, stream>>>(ctxb, wob, bo, bo, bo, d_out,
                                             d_out, d_out, 32, 8);
}

// Round 4
// 503.964 us; speedup vs baseline: 1.4127x; 1.0572x over previous
//
#include <hip/hip_runtime.h>

typedef unsigned int u32;
typedef unsigned short u16;
typedef __bf16 bf16x8 __attribute__((ext_vector_type(8)));
typedef float f32x4 __attribute__((ext_vector_type(4)));

// ---------- helpers ----------

__device__ __forceinline__ u16 f2bf(float f) {
  u32 u = __builtin_bit_cast(u32, f);
  u32 r = u + 0x7fffu + ((u >> 16) & 1u);  // RNE
  return (u16)(r >> 16);
}

__device__ __forceinline__ void gload_lds16(const void* g, void* l) {
  __builtin_amdgcn_global_load_lds(
      (__attribute__((address_space(1))) void*)(g),
      (__attribute__((address_space(3))) void*)(l), 16, 0, 0);
}

// ---------- fp32 -> bf16 conversion (hs + 4 weights) ----------

__global__ __launch_bounds__(256) void convert_kernel(
    const float* __restrict__ hs, const float* __restrict__ wq,
    const float* __restrict__ wk, const float* __restrict__ wv,
    const float* __restrict__ wo,
    u16* __restrict__ hsb, u16* __restrict__ wqb, u16* __restrict__ wkb,
    u16* __restrict__ wvb, u16* __restrict__ wob) {
  long t = (long)blockIdx.x * 256 + threadIdx.x;
  const float* src;
  u16* dst;
  long off;
  if (t < 2097152) {
    src = hs; dst = hsb; off = t << 3;
  } else {
    long u = t - 2097152;
    int wi = (int)(u >> 19);
    off = (u & 524287) << 3;
    if (wi == 0)      { src = wq; dst = wqb; }
    else if (wi == 1) { src = wk; dst = wkb; }
    else if (wi == 2) { src = wv; dst = wvb; }
    else              { src = wo; dst = wob; }
  }
  float4 a = *(const float4*)(src + off);
  float4 b = *(const float4*)(src + off + 4);
  uint4 o;
  o.x = (u32)f2bf(a.x) | ((u32)f2bf(a.y) << 16);
  o.y = (u32)f2bf(a.z) | ((u32)f2bf(a.w) << 16);
  o.z = (u32)f2bf(b.x) | ((u32)f2bf(b.y) << 16);
  o.w = (u32)f2bf(b.z) | ((u32)f2bf(b.w) << 16);
  *(uint4*)(dst + off) = o;
}

// ---------- 256x256 phase-split GEMM, BK=64, 8 waves, K=2048 ----------

template <int OF32>
__global__ __launch_bounds__(512, 2) void gemm256_kernel(
    const u16* __restrict__ A, const u16* __restrict__ Bw,
    const float* __restrict__ bias0, const float* __restrict__ bias1,
    const float* __restrict__ bias2, void* __restrict__ o0,
    void* __restrict__ o1, void* __restrict__ o2, int m_tiles, int n_tiles) {
  __shared__ __align__(16) char L[2][2][2][16384];  // [buf][op][khalf]

  const int tid = threadIdx.x;
  const int lane = tid & 63, w = tid >> 6;
  const int lr = lane & 15, lk = lane >> 4;
  const int wm = (w >> 2) * 128, wn = (w & 3) * 64;

  const int bid = blockIdx.x;
  const int xcd = bid & 7, loc = bid >> 3;
  const int n_idx = xcd * (n_tiles >> 3) + loc / m_tiles;
  const int m_idx = loc % m_tiles;
  const int m0 = m_idx * 256, n0 = n_idx * 256;

  const char* Ab = (const char*)A;
  const char* Bb = (const char*)Bw;

  auto stage = [&](int t, int kh, int isB) {
    const char* G = isB ? Bb : Ab;
    const int r0 = isB ? n0 : m0;
    char* Ld = &L[t & 1][isB][kh][0];
    const size_t kb = (size_t)(t * 64 + kh * 32) * 2;
#pragma unroll
    for (int j = 0; j < 2; j++) {
      const int o = j * 8192 + tid * 16;
      const int row = o >> 6;
      const int c = (o & 63) ^ (((row >> 1) & 3) << 4);
      gload_lds16(G + (size_t)(r0 + row) * 4096 + kb + c, Ld + o);
    }
  };
  auto rdA = [&](bf16x8* dst, int buf, int kh, int mset) {
#pragma unroll
    for (int m = 0; m < 4; m++) {
      const int row = wm + mset * 64 + m * 16 + lr;
      const int c = (lk * 16) ^ (((row >> 1) & 3) << 4);
      dst[m] = *(const bf16x8*)(&L[buf][0][kh][0] + row * 64 + c);
    }
  };
  auto rdB = [&](bf16x8* dst, int buf, int kh) {
#pragma unroll
    for (int n = 0; n < 4; n++) {
      const int row = wn + n * 16 + lr;
      const int c = (lk * 16) ^ (((row >> 1) & 3) << 4);
      dst[n] = *(const bf16x8*)(&L[buf][1][kh][0] + row * 64 + c);
    }
  };

  f32x4 acc[2][4][4];
#pragma unroll
  for (int s = 0; s < 2; s++)
#pragma unroll
    for (int m = 0; m < 4; m++)
#pragma unroll
      for (int n = 0; n < 4; n++) acc[s][m][n] = {0.f, 0.f, 0.f, 0.f};

  auto mm = [&](f32x4 (&ac)[4][4], bf16x8* a_, bf16x8* b_) {
    __builtin_amdgcn_s_setprio(1);
#pragma unroll
    for (int m = 0; m < 4; m++)
#pragma unroll
      for (int n = 0; n < 4; n++)
        ac[m][n] = __builtin_amdgcn_mfma_f32_16x16x32_bf16(a_[m], b_[n],
                                                           ac[m][n], 0, 0, 0);
    __builtin_amdgcn_s_setprio(0);
  };

  stage(0, 0, 0); stage(0, 0, 1); stage(0, 1, 0); stage(0, 1, 1);
  stage(1, 0, 0); stage(1, 0, 1);
  asm volatile("s_waitcnt vmcnt(4)" ::: "memory");
  asm volatile("s_barrier" ::: "memory");

  bf16x8 af[4], af2[4], bf[4];
  for (int t = 0; t < 32; ++t) {
    const int buf = t & 1;
    const int t1 = (t + 1 < 32) ? t + 1 : 31;
    const int t2 = (t + 2 < 32) ? t + 2 : 31;
    stage(t1, 1, 0);
    rdA(af, buf, 0, 0); rdB(bf, buf, 0);
    asm volatile("s_barrier" ::: "memory");
    mm(acc[0], af, bf);
    asm volatile("s_barrier" ::: "memory");
    stage(t1, 1, 1);
    rdA(af2, buf, 0, 1);
    asm volatile("s_barrier" ::: "memory");
    mm(acc[1], af2, bf);
    asm volatile("s_barrier" ::: "memory");
    stage(t2, 0, 0);
    rdA(af, buf, 1, 0); rdB(bf, buf, 1);
    asm volatile("s_barrier" ::: "memory");
    mm(acc[0], af, bf);
    asm volatile("s_barrier" ::: "memory");
    stage(t2, 0, 1);
    rdA(af2, buf, 1, 1);
    asm volatile("s_barrier" ::: "memory");
    mm(acc[1], af2, bf);
    asm volatile("s_waitcnt vmcnt(4)" ::: "memory");
    asm volatile("s_barrier" ::: "memory");
  }
  asm volatile("s_waitcnt vmcnt(0)" ::: "memory");

  const float* bias;
  void* op;
  int nl0;
  if (OF32) {
    bias = bias0; op = o0; nl0 = n0;
  } else {
    const int seg = n0 >> 11;
    bias = seg == 0 ? bias0 : (seg == 1 ? bias1 : bias2);
    op = seg == 0 ? o0 : (seg == 1 ? o1 : o2);
    nl0 = n0 & 2047;
  }
#pragma unroll
  for (int n = 0; n < 4; n++) {
    const int col = nl0 + wn + n * 16 + lr;
    const float bv = bias[col];
#pragma unroll
    for (int s = 0; s < 2; s++)
#pragma unroll
      for (int m = 0; m < 4; m++) {
        const int grow = m0 + wm + s * 64 + m * 16 + lk * 4;
#pragma unroll
        for (int r = 0; r < 4; r++) {
          const float v = acc[s][m][n][r] + bv;
          if (OF32)
            ((float*)op)[(size_t)(grow + r) * 2048 + col] = v;
          else
            ((u16*)op)[(size_t)(grow + r) * 2048 + col] = f2bf(v);
        }
      }
  }
}

// ---------- fused causal attention with alibi + tanh cap ----------
// 512 blocks x 512 threads (8 waves). Supertile pair (pi, 15-pi): 34 iters.
// LDS 64KB (single-buf K re-staged post-QK barrier, dbuf V^T, per-wave P)
// -> 2 blocks/CU. Softmax: Pade[5/4] tanh (1 rcp + 1 exp2 per element).

__global__ __launch_bounds__(512, 2) void attn_kernel(
    const u16* __restrict__ Qm, const u16* __restrict__ Km,
    const u16* __restrict__ Vm, const float* __restrict__ slopes,
    u16* __restrict__ ctx) {
  __shared__ __align__(16) char Ks[64 * 256];      // 16 KB, xor-swizzled rows
  __shared__ __align__(16) char Vt[2][128 * 128];  // 32 KB, V^T xor-swizzled
  __shared__ __align__(16) char Pb[8][16 * 128];   // 16 KB, per-wave P

  const int bid = blockIdx.x;
  const int sw = (bid & 7) * 64 + (bid >> 3);
  const int bh = sw >> 3, pi = sw & 7;
  const int b = bh >> 4, h = bh & 15;
  const int NTA = 2 * pi + 2;

  const int tid = threadIdx.x;
  const int lane = tid & 63, w = tid >> 6;
  const int lr = lane & 15, lk = lane >> 4;

  const char* Qb = (const char*)Qm + (size_t)b * 2048 * 4096 + h * 256;
  const char* Kb = (const char*)Km + (size_t)b * 2048 * 4096 + h * 256;
  const char* Vb = (const char*)Vm + (size_t)b * 2048 * 4096 + h * 256;

  const float SCALE = 0.08838834764831845f;  // 1/sqrt(128)
  const float sl_c = slopes[h] * SCALE;

  // Pade[5/4] of 30*tanh(z/30), log2e folded into numerator; exp2 shift
  const float A0 = 1363.3468136400704f, A2 = 0.16831442143704573f,
              A4 = 1.7811049887518067e-6f;
  const float D0 = 945.0f, D2 = 0.4666666666666667f, D4 = 1.851851851851852e-5f;
  const float SH = -43.2808512266689f;  // -30*log2(e)

  float Tt[16];
#pragma unroll
  for (int nb = 0; nb < 4; nb++)
#pragma unroll
    for (int r = 0; r < 4; r++) Tt[nb * 4 + r] = sl_c * (float)(nb * 16 - r);

  const int vd0 = (tid & 15) * 8;
  const int vkv2 = tid >> 4;

  uint4 vr0, vr1;

  auto kvt_of = [&](int it) { return it < NTA ? it : it - NTA; };

  auto stageK = [&](int it) {
    const int kv0 = kvt_of(it) * 64;
#pragma unroll
    for (int j = 0; j < 2; j++) {
      const int o = j * 8192 + tid * 16;
      const int row = o >> 8, c = (o & 255) ^ ((row & 7) << 4);
      gload_lds16(Kb + (size_t)(kv0 + row) * 4096 + c, Ks + o);
    }
  };
  auto loadV = [&](int it) {
    const int kv0 = kvt_of(it) * 64;
    vr0 = *(const uint4*)(Vb + (size_t)(kv0 + vkv2 * 2) * 4096 + vd0 * 2);
    vr1 = *(const uint4*)(Vb + (size_t)(kv0 + vkv2 * 2 + 1) * 4096 + vd0 * 2);
  };
  auto writeV = [&](int bufi) {
    const u32* p0 = (const u32*)&vr0;
    const u32* p1 = (const u32*)&vr1;
#pragma unroll
    for (int wd = 0; wd < 4; wd++) {
      const u32 ev = __builtin_amdgcn_perm(p1[wd], p0[wd], 0x05040100u);
      const u32 od = __builtin_amdgcn_perm(p1[wd], p0[wd], 0x07060302u);
      const int d0_ = vd0 + 2 * wd, d1_ = d0_ + 1;
      *(u32*)(Vt[bufi] + d0_ * 128 +
              ((vkv2 * 4) ^ (((d0_ ^ (d0_ >> 3)) & 7) << 4))) = ev;
      *(u32*)(Vt[bufi] + d1_ * 128 +
              ((vkv2 * 4) ^ (((d1_ ^ (d1_ >> 3)) & 7) << 4))) = od;
    }
  };

  bf16x8 qf[4];
  f32x4 pv[8];
  float rs[4];
  int q0 = 0;

  stageK(0);
  loadV(0);

  for (int it = 0; it < 34; ++it) {
    const int bufi = it & 1;
    const int kv0 = kvt_of(it) * 64;

    if (it == 0 || it == NTA) {  // block-uniform: (re)load Q, reset acc
      const int st = (it == 0) ? pi : (15 - pi);
      q0 = st * 128 + w * 16;
#pragma unroll
      for (int kc = 0; kc < 4; kc++)
        qf[kc] =
            *(const bf16x8*)(Qb + (size_t)(q0 + lr) * 4096 + kc * 64 + lk * 16);
#pragma unroll
      for (int i = 0; i < 8; i++) pv[i] = {0.f, 0.f, 0.f, 0.f};
      rs[0] = rs[1] = rs[2] = rs[3] = 0.f;
    }

    writeV(bufi);  // V(it) regs -> Vt[bufi] (implicit vmcnt wait on vr)
    asm volatile("s_waitcnt vmcnt(0)" ::: "memory");  // drain stageK(it)
    __syncthreads();  // Ks + Vt[bufi] visible to all

    if (it + 1 < 34) loadV(it + 1);  // V prefetch (regs), in flight

    // S = Q K^T
    f32x4 sc[4];
    __builtin_amdgcn_s_setprio(1);
#pragma unroll
    for (int nb = 0; nb < 4; nb++) {
      f32x4 a = {0.f, 0.f, 0.f, 0.f};
      const int krow = nb * 16 + lr;
#pragma unroll
      for (int kc = 0; kc < 4; kc++) {
        const int off = krow * 256 + ((kc * 64 + lk * 16) ^ ((krow & 7) << 4));
        bf16x8 kf = *(const bf16x8*)(Ks + off);
        a = __builtin_amdgcn_mfma_f32_16x16x32_bf16(qf[kc], kf, a, 0, 0, 0);
      }
      sc[nb] = a;
    }
    __builtin_amdgcn_s_setprio(0);

    __syncthreads();                 // all QK reads of Ks done
    if (it + 1 < 34) stageK(it + 1);  // K prefetch into Ks (hidden under
                                      // softmax+PV, drained at next top)

    // softmax: z = sc*SCALE + alibi; capped*log2e = z*num(u)/den(u); p=exp2
    const float aliB = sl_c * (float)(kv0 + lr - q0 - lk * 4);
#pragma unroll
    for (int nb = 0; nb < 4; nb++) {
      const int kv = kv0 + nb * 16 + lr;
#pragma unroll
      for (int r = 0; r < 4; r++) {
        const int q = q0 + lk * 4 + r;
        const float z = fmaf(sc[nb][r], SCALE, aliB + Tt[nb * 4 + r]);
        const float u = z * z;
        const float num = fmaf(u, fmaf(u, A4, A2), A0);
        const float den = fmaf(u, fmaf(u, D4, D2), D0);
        const float pa = fmaf(z * num, __builtin_amdgcn_rcpf(den), SH);
        float p = exp2f(pa);
        p = (kv <= q) ? p : 0.0f;
        rs[r] += p;
        const int qq = lk * 4 + r;
        const int off =
            qq * 128 + (((nb * 16 + lr) * 2) ^ ((qq & 12) << 3));
        const u32 ub = __builtin_bit_cast(u32, p);
        *(u16*)(Pb[w] + off) = (u16)((ub + 0x8000u) >> 16);
      }
    }

    // ctx += P V
    __builtin_amdgcn_s_setprio(1);
#pragma unroll
    for (int kc = 0; kc < 2; kc++) {
      const int poff = lr * 128 + ((kc * 64 + lk * 16) ^ ((lr & 12) << 3));
      bf16x8 pf = *(const bf16x8*)(Pb[w] + poff);
#pragma unroll
      for (int db = 0; db < 8; db++) {
        const int d = db * 16 + lr;
        const int voff =
            d * 128 + ((kc * 64 + lk * 16) ^ (((d ^ (d >> 3)) & 7) << 4));
        bf16x8 vf = *(const bf16x8*)(Vt[bufi] + voff);
        pv[db] = __builtin_amdgcn_mfma_f32_16x16x32_bf16(pf, vf, pv[db], 0, 0, 0);
      }
    }
    __builtin_amdgcn_s_setprio(0);

    if (it == NTA - 1 || it == 33) {  // finalize current supertile
      float inv[4];
#pragma unroll
      for (int r = 0; r < 4; r++) {
        float s = rs[r];
        s += __shfl_xor(s, 1);
        s += __shfl_xor(s, 2);
        s += __shfl_xor(s, 4);
        s += __shfl_xor(s, 8);
        inv[r] = 1.0f / s;
      }
      const size_t baserow = (size_t)b * 2048 + q0 + lk * 4;
#pragma unroll
      for (int db = 0; db < 8; db++)
#pragma unroll
        for (int r = 0; r < 4; r++)
          ctx[(baserow + r) * 2048 + h * 128 + db * 16 + lr] =
              f2bf(pv[db][r] * inv[r]);
    }
  }
}

// ---------- launcher ----------

extern "C" void kernel_launch(void* const* d_in, const int* in_sizes, int n_in,
                              void* d_out, int out_size, void* d_ws,
                              size_t ws_size, hipStream_t stream) {
  const float* hs = (const float*)d_in[0];
  const float* Wq = (const float*)d_in[1];
  const float* bq = (const float*)d_in[2];
  const float* Wk = (const float*)d_in[3];
  const float* bk = (const float*)d_in[4];
  const float* Wv = (const float*)d_in[5];
  const float* bv = (const float*)d_in[6];
  const float* Wo = (const float*)d_in[7];
  const float* bo = (const float*)d_in[8];
  const float* slopes = (const float*)d_in[9];

  char* ws = (char*)d_ws;
  u16* hsb = (u16*)(ws);                 // reused as ctx after QKV
  u16* wqb = (u16*)(ws + 33554432);      // wq|wk|wv contiguous => [6144][2048]
  u16* wkb = (u16*)(ws + 41943040);
  u16* wvb = (u16*)(ws + 50331648);
  u16* wob = (u16*)(ws + 58720256);
  u16* Qb  = (u16*)(ws + 67108864);
  u16* Kb  = (u16*)(ws + 100663296);
  u16* Vb  = (u16*)(ws + 134217728);
  u16* ctxb = hsb;

  convert_kernel<<<16384, 256, 0, stream>>>(hs, Wq, Wk, Wv, Wo, hsb, wqb, wkb,
                                            wvb, wob);
  gemm256_kernel<0><<<768, 512, 0, stream>>>(hsb, wqb, bq, bk, bv, Qb, Kb, Vb,
                                             32, 24);
  attn_kernel<<<512, 512, 0, stream>>>(Qb, Kb, Vb, slopes, ctxb);
  gemm256_kernel<1><<<256, 512, 0, stream>>>(ctxb, wob, bo, bo, bo, d_out,
                                             d_out, d_out, 32, 8);
}